// Round 1
// baseline (566.962 us; speedup 1.0000x reference)
//
#include <hip/hip_runtime.h>

#define N_NODES 50000
#define N_EDGES 1000000
#define D 64
#define L 3
#define BN_EPS 1e-5f

// ---------------------------------------------------------------- init
__global__ void init_kernel(int* __restrict__ counts, float* __restrict__ bnsum) {
    int i = blockIdx.x * blockDim.x + threadIdx.x;
    int stride = gridDim.x * blockDim.x;
    for (int j = i; j < N_NODES; j += stride) counts[j] = 0;
    for (int j = i; j < L * 2 * D; j += stride) bnsum[j] = 0.f;
}

// ---------------------------------------------------------------- CSR build
__global__ void count_kernel(const int* __restrict__ dst, int* __restrict__ counts) {
    int i = blockIdx.x * blockDim.x + threadIdx.x;
    int stride = gridDim.x * blockDim.x;
    for (int e = i; e < N_EDGES; e += stride) atomicAdd(&counts[dst[e]], 1);
}

// single-block scan: 1024 threads x 49 elements each covers 50176 >= N_NODES
__global__ __launch_bounds__(1024) void scan_kernel(const int* __restrict__ counts,
                                                    int* __restrict__ row_ptr,
                                                    int* __restrict__ cursor) {
    const int PER = (N_NODES + 1023) / 1024;  // 49
    __shared__ int buf[1024];
    int t = threadIdx.x;
    int base = t * PER;
    int s = 0;
    for (int j = 0; j < PER; j++) {
        int idx = base + j;
        if (idx < N_NODES) s += counts[idx];
    }
    buf[t] = s;
    __syncthreads();
    for (int off = 1; off < 1024; off <<= 1) {
        int v = (t >= off) ? buf[t - off] : 0;
        __syncthreads();
        buf[t] += v;
        __syncthreads();
    }
    int excl = buf[t] - s;  // exclusive prefix of this thread's chunk
    for (int j = 0; j < PER; j++) {
        int idx = base + j;
        if (idx < N_NODES) {
            row_ptr[idx] = excl;
            cursor[idx] = excl;
            excl += counts[idx];
        }
    }
    if (t == 1023) row_ptr[N_NODES] = buf[1023];
}

__global__ void fill_kernel(const int* __restrict__ src, const int* __restrict__ dst,
                            const float* __restrict__ w, int* __restrict__ cursor,
                            int* __restrict__ src_s, float* __restrict__ w_s) {
    int i = blockIdx.x * blockDim.x + threadIdx.x;
    int stride = gridDim.x * blockDim.x;
    for (int e = i; e < N_EDGES; e += stride) {
        int d = dst[e];
        int p = atomicAdd(&cursor[d], 1);
        src_s[p] = src[e];
        w_s[p] = w[e];
    }
}

// ---------------------------------------------------------------- GEMM
// xw[v][c] = sum_k (hraw[v][k]*scale[k]+shift[k]) * W[k][c]
// Folds the affine into Wreg and a per-column bias. Lane = output column c.
// h-row reads are wave-uniform -> scalar loads.
__global__ __launch_bounds__(256) void gemm_kernel(const float* __restrict__ hraw,
                                                   const float* __restrict__ affine,
                                                   const float* __restrict__ Wl,
                                                   float* __restrict__ xw) {
    int tid = threadIdx.x, lane = tid & 63, wave = tid >> 6;
    float Wreg[D];
    float biasc = 0.f;
#pragma unroll
    for (int k = 0; k < D; k++) {
        float wkc = Wl[k * D + lane];
        float sck = affine ? affine[k] : 1.f;
        float shk = affine ? affine[D + k] : 0.f;
        biasc = fmaf(shk, wkc, biasc);
        Wreg[k] = wkc * sck;
    }
    int gw = blockIdx.x * 4 + wave, nw = gridDim.x * 4;
    for (int v = gw; v < N_NODES; v += nw) {
        const float* hp = hraw + (size_t)__builtin_amdgcn_readfirstlane(v) * D;
        float acc = biasc;
#pragma unroll
        for (int k = 0; k < D; k++) acc = fmaf(hp[k], Wreg[k], acc);
        xw[v * D + lane] = acc;
    }
}

// ---------------------------------------------------------------- aggregate
// One wave per dst node, lane = feature. acc = b + sum_e w_e * xw[src_e][lane];
// PReLU; + residual (affine of previous hpre); write hpre; accumulate BN sums.
__global__ __launch_bounds__(256) void agg_kernel(const float* __restrict__ xw,
                                                  const int* __restrict__ row_ptr,
                                                  const int* __restrict__ src_s,
                                                  const float* __restrict__ w_s,
                                                  const float* __restrict__ bl,
                                                  const float* __restrict__ pa,
                                                  const float* __restrict__ hraw_prev,
                                                  const float* __restrict__ affine_prev,
                                                  float* __restrict__ hpre,
                                                  float* __restrict__ bnsum) {
    int tid = threadIdx.x, lane = tid & 63, wave = tid >> 6;
    int gw = blockIdx.x * 4 + wave, nw = gridDim.x * 4;
    float al = pa[0];
    float bias = bl[lane];
    float sc = 0.f, sh = 0.f;
    if (hraw_prev) { sc = affine_prev[lane]; sh = affine_prev[D + lane]; }
    float s1 = 0.f, s2 = 0.f;
    for (int v = gw; v < N_NODES; v += nw) {
        int e0 = row_ptr[v], e1 = row_ptr[v + 1];
        float acc = bias;
        int e = e0;
        for (; e + 4 <= e1; e += 4) {
            int i0 = src_s[e], i1 = src_s[e + 1], i2 = src_s[e + 2], i3 = src_s[e + 3];
            float w0 = w_s[e], w1 = w_s[e + 1], w2 = w_s[e + 2], w3 = w_s[e + 3];
            float x0 = xw[i0 * D + lane];
            float x1 = xw[i1 * D + lane];
            float x2 = xw[i2 * D + lane];
            float x3 = xw[i3 * D + lane];
            acc = fmaf(w0, x0, acc);
            acc = fmaf(w1, x1, acc);
            acc = fmaf(w2, x2, acc);
            acc = fmaf(w3, x3, acc);
        }
        for (; e < e1; e++) acc = fmaf(w_s[e], xw[src_s[e] * D + lane], acc);
        float h = acc >= 0.f ? acc : al * acc;
        if (hraw_prev) h = fmaf(hraw_prev[v * D + lane], sc, h + sh);
        hpre[v * D + lane] = h;
        s1 += h;
        s2 = fmaf(h, h, s2);
    }
    __shared__ float red[8][D];
    red[wave][lane] = s1;
    red[4 + wave][lane] = s2;
    __syncthreads();
    if (wave == 0) {
        float t1 = red[0][lane] + red[1][lane] + red[2][lane] + red[3][lane];
        float t2 = red[4][lane] + red[5][lane] + red[6][lane] + red[7][lane];
        atomicAdd(&bnsum[lane], t1);
        atomicAdd(&bnsum[D + lane], t2);
    }
}

// ---------------------------------------------------------------- BN params
__global__ void bnparam_kernel(const float* __restrict__ bnsum, const float* __restrict__ gamma,
                               const float* __restrict__ beta, float* __restrict__ affine) {
    int c = threadIdx.x;
    if (c < D) {
        float mean = bnsum[c] * (1.f / N_NODES);
        float var = bnsum[D + c] * (1.f / N_NODES) - mean * mean;
        float inv = rsqrtf(var + BN_EPS);
        float scg = gamma[c] * inv;
        affine[c] = scg;
        affine[D + c] = beta[c] - mean * scg;
    }
}

// ---------------------------------------------------------------- final BN apply
__global__ void bnapply_kernel(const float* __restrict__ hpre, const float* __restrict__ affine,
                               float* __restrict__ out) {
    int i = blockIdx.x * blockDim.x + threadIdx.x;
    int stride = gridDim.x * blockDim.x;
    const int NQ = N_NODES * D / 4;
    for (int j = i; j < NQ; j += stride) {
        float4 hv = ((const float4*)hpre)[j];
        int c = (j * 4) & 63;
        float4 o;
        o.x = fmaf(hv.x, affine[c + 0], affine[D + c + 0]);
        o.y = fmaf(hv.y, affine[c + 1], affine[D + c + 1]);
        o.z = fmaf(hv.z, affine[c + 2], affine[D + c + 2]);
        o.w = fmaf(hv.w, affine[c + 3], affine[D + c + 3]);
        ((float4*)out)[j] = o;
    }
}

// ---------------------------------------------------------------- launch
extern "C" void kernel_launch(void* const* d_in, const int* in_sizes, int n_in,
                              void* d_out, int out_size, void* d_ws, size_t ws_size,
                              hipStream_t stream) {
    const float* x     = (const float*)d_in[0];
    const int*   esrc  = (const int*)d_in[1];
    const int*   edst  = (const int*)d_in[2];
    const float* ew    = (const float*)d_in[3];
    const float* W     = (const float*)d_in[4];
    const float* b     = (const float*)d_in[5];
    const float* pa    = (const float*)d_in[6];
    const float* gamma = (const float*)d_in[7];
    const float* beta  = (const float*)d_in[8];
    float* out = (float*)d_out;

    char* ws = (char*)d_ws;
    size_t off = 0;
    auto alloc = [&](size_t bytes) -> char* {
        char* p = ws + off;
        off = (off + bytes + 255) & ~(size_t)255;
        return p;
    };
    int*   counts  = (int*)alloc((size_t)N_NODES * 4);
    int*   row_ptr = (int*)alloc((size_t)(N_NODES + 1) * 4);
    int*   cursor  = (int*)alloc((size_t)N_NODES * 4);
    int*   src_s   = (int*)alloc((size_t)N_EDGES * 4);
    float* w_s     = (float*)alloc((size_t)N_EDGES * 4);
    float* xw      = (float*)alloc((size_t)N_NODES * D * 4);
    float* hpre1   = (float*)alloc((size_t)N_NODES * D * 4);
    float* bnsum   = (float*)alloc((size_t)L * 2 * D * 4);
    float* affine  = (float*)alloc((size_t)L * 2 * D * 4);

    init_kernel<<<256, 256, 0, stream>>>(counts, bnsum);
    count_kernel<<<2048, 256, 0, stream>>>(edst, counts);
    scan_kernel<<<1, 1024, 0, stream>>>(counts, row_ptr, cursor);
    fill_kernel<<<2048, 256, 0, stream>>>(esrc, edst, ew, cursor, src_s, w_s);

    // hpre storage: layer0 -> d_out, layer1 -> ws, layer2 -> d_out
    float* hbuf[L] = {out, hpre1, out};
    for (int i = 0; i < L; i++) {
        const float* hin      = (i == 0) ? x : hbuf[i - 1];
        const float* aff_prev = (i == 0) ? nullptr : affine + (i - 1) * 2 * D;
        gemm_kernel<<<512, 256, 0, stream>>>(hin, aff_prev, W + (size_t)i * D * D, xw);
        agg_kernel<<<2048, 256, 0, stream>>>(xw, row_ptr, src_s, w_s, b + i * D, pa + i,
                                             (i == 0) ? nullptr : hbuf[i - 1], aff_prev,
                                             hbuf[i], bnsum + i * 2 * D);
        bnparam_kernel<<<1, 64, 0, stream>>>(bnsum + i * 2 * D, gamma + i * D, beta + i * D,
                                             affine + i * 2 * D);
    }
    bnapply_kernel<<<2048, 256, 0, stream>>>(hbuf[2], affine + 2 * 2 * D, out);
}

// Round 2
// 428.567 us; speedup vs baseline: 1.3229x; 1.3229x over previous
//
#include <hip/hip_runtime.h>

#define N_NODES 50000
#define N_EDGES 1000000
#define D 64
#define L 3
#define BN_EPS 1e-5f
#define NB_SCAN ((N_NODES + 255) / 256)  // 196 blocks of 256

// ---------------------------------------------------------------- helpers
__device__ inline void bn_affine(const float* __restrict__ bnsum,
                                 const float* __restrict__ gamma,
                                 const float* __restrict__ beta,
                                 int c, float& sc, float& sh) {
    float mean = bnsum[c] * (1.f / N_NODES);
    float var = fmaf(-mean, mean, bnsum[D + c] * (1.f / N_NODES));
    float inv = rsqrtf(var + BN_EPS);
    sc = gamma[c] * inv;
    sh = fmaf(-mean, sc, beta[c]);
}

// ---------------------------------------------------------------- init
__global__ void init_kernel(int* __restrict__ counts, float* __restrict__ bnsum) {
    int i = blockIdx.x * blockDim.x + threadIdx.x;
    int stride = gridDim.x * blockDim.x;
    for (int j = i; j < N_NODES; j += stride) counts[j] = 0;
    for (int j = i; j < L * 2 * D; j += stride) bnsum[j] = 0.f;
}

// ---------------------------------------------------------------- CSR build
__global__ void count_kernel(const int* __restrict__ dst, int* __restrict__ counts) {
    int i = blockIdx.x * blockDim.x + threadIdx.x;
    int stride = gridDim.x * blockDim.x;
    for (int e = i; e < N_EDGES; e += stride) atomicAdd(&counts[dst[e]], 1);
}

// phase A: per-block (256-wide) reduction of counts -> blocksum[b]
__global__ __launch_bounds__(256) void scanA_kernel(const int* __restrict__ counts,
                                                    int* __restrict__ blocksum) {
    __shared__ int buf[256];
    int t = threadIdx.x, b = blockIdx.x;
    int i = b * 256 + t;
    int v = (i < N_NODES) ? counts[i] : 0;
    buf[t] = v;
    __syncthreads();
    for (int off = 128; off > 0; off >>= 1) {
        if (t < off) buf[t] += buf[t + off];
        __syncthreads();
    }
    if (t == 0) blocksum[b] = buf[0];
}

// phase B: single small block scans the NB_SCAN block sums -> exclusive blockoff
__global__ __launch_bounds__(256) void scanB_kernel(const int* __restrict__ blocksum,
                                                    int* __restrict__ blockoff,
                                                    int* __restrict__ row_ptr) {
    __shared__ int buf[256];
    int t = threadIdx.x;
    int v = (t < NB_SCAN) ? blocksum[t] : 0;
    buf[t] = v;
    __syncthreads();
    for (int off = 1; off < 256; off <<= 1) {
        int u = (t >= off) ? buf[t - off] : 0;
        __syncthreads();
        buf[t] += u;
        __syncthreads();
    }
    if (t < NB_SCAN) blockoff[t] = buf[t] - v;  // exclusive
    if (t == NB_SCAN - 1) row_ptr[N_NODES] = buf[t];
}

// phase C: per-block exclusive scan + add block offset -> row_ptr, cursor
__global__ __launch_bounds__(256) void scanC_kernel(const int* __restrict__ counts,
                                                    const int* __restrict__ blockoff,
                                                    int* __restrict__ row_ptr,
                                                    int* __restrict__ cursor) {
    __shared__ int buf[256];
    int t = threadIdx.x, b = blockIdx.x;
    int i = b * 256 + t;
    int v = (i < N_NODES) ? counts[i] : 0;
    buf[t] = v;
    __syncthreads();
    for (int off = 1; off < 256; off <<= 1) {
        int u = (t >= off) ? buf[t - off] : 0;
        __syncthreads();
        buf[t] += u;
        __syncthreads();
    }
    if (i < N_NODES) {
        int e = blockoff[b] + buf[t] - v;
        row_ptr[i] = e;
        cursor[i] = e;
    }
}

__global__ void fill_kernel(const int* __restrict__ src, const int* __restrict__ dst,
                            const float* __restrict__ w, int* __restrict__ cursor,
                            int* __restrict__ src_s, float* __restrict__ w_s) {
    int i = blockIdx.x * blockDim.x + threadIdx.x;
    int stride = gridDim.x * blockDim.x;
    for (int e = i; e < N_EDGES; e += stride) {
        int d = dst[e];
        int p = atomicAdd(&cursor[d], 1);
        src_s[p] = src[e];
        w_s[p] = w[e];
    }
}

// ---------------------------------------------------------------- GEMM
// xw[v][c] = sum_k (hraw[v][k]*scale[k]+shift[k]) * W[k][c]
// Affine recomputed from bnsum/gamma/beta in LDS (folds prev-layer BN).
__global__ __launch_bounds__(256) void gemm_kernel(const float* __restrict__ hraw,
                                                   const float* __restrict__ bnsum_p,
                                                   const float* __restrict__ gamma_p,
                                                   const float* __restrict__ beta_p,
                                                   const float* __restrict__ Wl,
                                                   float* __restrict__ xw) {
    __shared__ float aff[2][D];
    int tid = threadIdx.x, lane = tid & 63, wave = tid >> 6;
    if (tid < D) {
        float sc = 1.f, sh = 0.f;
        if (bnsum_p) bn_affine(bnsum_p, gamma_p, beta_p, tid, sc, sh);
        aff[0][tid] = sc;
        aff[1][tid] = sh;
    }
    __syncthreads();
    float Wreg[D];
    float biasc = 0.f;
#pragma unroll
    for (int k = 0; k < D; k++) {
        float wkc = Wl[k * D + lane];
        biasc = fmaf(aff[1][k], wkc, biasc);
        Wreg[k] = wkc * aff[0][k];
    }
    int gw = blockIdx.x * 4 + wave, nw = gridDim.x * 4;
    for (int v = gw; v < N_NODES; v += nw) {
        const float* hp = hraw + (size_t)__builtin_amdgcn_readfirstlane(v) * D;
        float acc = biasc;
#pragma unroll
        for (int k = 0; k < D; k++) acc = fmaf(hp[k], Wreg[k], acc);
        xw[v * D + lane] = acc;
    }
}

// ---------------------------------------------------------------- aggregate
// One wave per dst node, lane = feature. acc = b + sum_e w_e * xw[src_e][lane];
// PReLU; + residual (affine of previous hpre); write hpre; accumulate BN sums.
__global__ __launch_bounds__(256) void agg_kernel(const float* __restrict__ xw,
                                                  const int* __restrict__ row_ptr,
                                                  const int* __restrict__ src_s,
                                                  const float* __restrict__ w_s,
                                                  const float* __restrict__ bl,
                                                  const float* __restrict__ pa,
                                                  const float* __restrict__ hraw_prev,
                                                  const float* __restrict__ bnsum_p,
                                                  const float* __restrict__ gamma_p,
                                                  const float* __restrict__ beta_p,
                                                  float* __restrict__ hpre,
                                                  float* __restrict__ bnsum) {
    int tid = threadIdx.x, lane = tid & 63, wave = tid >> 6;
    int gw = blockIdx.x * 4 + wave, nw = gridDim.x * 4;
    float al = pa[0];
    float bias = bl[lane];
    float sc = 0.f, sh = 0.f;
    if (hraw_prev) bn_affine(bnsum_p, gamma_p, beta_p, lane, sc, sh);
    float s1 = 0.f, s2 = 0.f;
    for (int v = gw; v < N_NODES; v += nw) {
        int e0 = row_ptr[v], e1 = row_ptr[v + 1];
        float acc = bias;
        int e = e0;
        for (; e + 4 <= e1; e += 4) {
            int i0 = src_s[e], i1 = src_s[e + 1], i2 = src_s[e + 2], i3 = src_s[e + 3];
            float w0 = w_s[e], w1 = w_s[e + 1], w2 = w_s[e + 2], w3 = w_s[e + 3];
            float x0 = xw[i0 * D + lane];
            float x1 = xw[i1 * D + lane];
            float x2 = xw[i2 * D + lane];
            float x3 = xw[i3 * D + lane];
            acc = fmaf(w0, x0, acc);
            acc = fmaf(w1, x1, acc);
            acc = fmaf(w2, x2, acc);
            acc = fmaf(w3, x3, acc);
        }
        for (; e < e1; e++) acc = fmaf(w_s[e], xw[src_s[e] * D + lane], acc);
        float h = acc >= 0.f ? acc : al * acc;
        if (hraw_prev) h = fmaf(hraw_prev[v * D + lane], sc, h + sh);
        hpre[v * D + lane] = h;
        s1 += h;
        s2 = fmaf(h, h, s2);
    }
    __shared__ float red[8][D];
    red[wave][lane] = s1;
    red[4 + wave][lane] = s2;
    __syncthreads();
    if (wave == 0) {
        float t1 = red[0][lane] + red[1][lane] + red[2][lane] + red[3][lane];
        float t2 = red[4][lane] + red[5][lane] + red[6][lane] + red[7][lane];
        atomicAdd(&bnsum[lane], t1);
        atomicAdd(&bnsum[D + lane], t2);
    }
}

// ---------------------------------------------------------------- final BN apply
__global__ __launch_bounds__(256) void bnapply_kernel(const float* __restrict__ hpre,
                                                      const float* __restrict__ bnsum_p,
                                                      const float* __restrict__ gamma_p,
                                                      const float* __restrict__ beta_p,
                                                      float* __restrict__ out) {
    __shared__ float aff[2][D];
    int tid = threadIdx.x;
    if (tid < D) {
        float sc, sh;
        bn_affine(bnsum_p, gamma_p, beta_p, tid, sc, sh);
        aff[0][tid] = sc;
        aff[1][tid] = sh;
    }
    __syncthreads();
    int i = blockIdx.x * blockDim.x + tid;
    int stride = gridDim.x * blockDim.x;
    const int NQ = N_NODES * D / 4;
    for (int j = i; j < NQ; j += stride) {
        float4 hv = ((const float4*)hpre)[j];
        int c = (j * 4) & 63;
        float4 o;
        o.x = fmaf(hv.x, aff[0][c + 0], aff[1][c + 0]);
        o.y = fmaf(hv.y, aff[0][c + 1], aff[1][c + 1]);
        o.z = fmaf(hv.z, aff[0][c + 2], aff[1][c + 2]);
        o.w = fmaf(hv.w, aff[0][c + 3], aff[1][c + 3]);
        ((float4*)out)[j] = o;
    }
}

// ---------------------------------------------------------------- launch
extern "C" void kernel_launch(void* const* d_in, const int* in_sizes, int n_in,
                              void* d_out, int out_size, void* d_ws, size_t ws_size,
                              hipStream_t stream) {
    const float* x     = (const float*)d_in[0];
    const int*   esrc  = (const int*)d_in[1];
    const int*   edst  = (const int*)d_in[2];
    const float* ew    = (const float*)d_in[3];
    const float* W     = (const float*)d_in[4];
    const float* b     = (const float*)d_in[5];
    const float* pa    = (const float*)d_in[6];
    const float* gamma = (const float*)d_in[7];
    const float* beta  = (const float*)d_in[8];
    float* out = (float*)d_out;

    char* ws = (char*)d_ws;
    size_t off = 0;
    auto alloc = [&](size_t bytes) -> char* {
        char* p = ws + off;
        off = (off + bytes + 255) & ~(size_t)255;
        return p;
    };
    int*   counts   = (int*)alloc((size_t)N_NODES * 4);
    int*   row_ptr  = (int*)alloc((size_t)(N_NODES + 1) * 4);
    int*   cursor   = (int*)alloc((size_t)N_NODES * 4);
    int*   blocksum = (int*)alloc((size_t)NB_SCAN * 4);
    int*   blockoff = (int*)alloc((size_t)NB_SCAN * 4);
    int*   src_s    = (int*)alloc((size_t)N_EDGES * 4);
    float* w_s      = (float*)alloc((size_t)N_EDGES * 4);
    float* xw       = (float*)alloc((size_t)N_NODES * D * 4);
    float* hpre1    = (float*)alloc((size_t)N_NODES * D * 4);
    float* bnsum    = (float*)alloc((size_t)L * 2 * D * 4);

    init_kernel<<<256, 256, 0, stream>>>(counts, bnsum);
    count_kernel<<<2048, 256, 0, stream>>>(edst, counts);
    scanA_kernel<<<NB_SCAN, 256, 0, stream>>>(counts, blocksum);
    scanB_kernel<<<1, 256, 0, stream>>>(blocksum, blockoff, row_ptr);
    scanC_kernel<<<NB_SCAN, 256, 0, stream>>>(counts, blockoff, row_ptr, cursor);
    fill_kernel<<<2048, 256, 0, stream>>>(esrc, edst, ew, cursor, src_s, w_s);

    // hpre storage: layer0 -> d_out, layer1 -> ws, layer2 -> d_out
    float* hbuf[L] = {out, hpre1, out};
    for (int i = 0; i < L; i++) {
        const float* hin = (i == 0) ? x : hbuf[i - 1];
        const float* bns = (i == 0) ? nullptr : bnsum + (i - 1) * 2 * D;
        const float* gmp = (i == 0) ? nullptr : gamma + (i - 1) * D;
        const float* btp = (i == 0) ? nullptr : beta + (i - 1) * D;
        gemm_kernel<<<512, 256, 0, stream>>>(hin, bns, gmp, btp, W + (size_t)i * D * D, xw);
        agg_kernel<<<2048, 256, 0, stream>>>(xw, row_ptr, src_s, w_s, b + i * D, pa + i,
                                             (i == 0) ? nullptr : hbuf[i - 1],
                                             bns, gmp, btp,
                                             hbuf[i], bnsum + i * 2 * D);
    }
    bnapply_kernel<<<2048, 256, 0, stream>>>(hbuf[2], bnsum + 2 * 2 * D,
                                             gamma + 2 * D, beta + 2 * D, out);
}

// Round 3
// 406.153 us; speedup vs baseline: 1.3959x; 1.0552x over previous
//
#include <hip/hip_runtime.h>
#include <hip/hip_fp16.h>

#define N_NODES 50000
#define N_EDGES 1000000
#define D 64
#define L 3
#define BN_EPS 1e-5f
#define NB_SCAN ((N_NODES + 255) / 256)  // 196 blocks of 256

// ---------------------------------------------------------------- helpers
__device__ inline void bn_affine(const float* __restrict__ bnsum,
                                 const float* __restrict__ gamma,
                                 const float* __restrict__ beta,
                                 int c, float& sc, float& sh) {
    float mean = bnsum[c] * (1.f / N_NODES);
    float var = fmaf(-mean, mean, bnsum[D + c] * (1.f / N_NODES));
    float inv = rsqrtf(var + BN_EPS);
    sc = gamma[c] * inv;
    sh = fmaf(-mean, sc, beta[c]);
}

// ---------------------------------------------------------------- init
__global__ void init_kernel(int* __restrict__ counts, float* __restrict__ bnsum) {
    int i = blockIdx.x * blockDim.x + threadIdx.x;
    int stride = gridDim.x * blockDim.x;
    for (int j = i; j < N_NODES; j += stride) counts[j] = 0;
    for (int j = i; j < L * 2 * D; j += stride) bnsum[j] = 0.f;
}

// ---------------------------------------------------------------- CSR build
__global__ void count_kernel(const int* __restrict__ dst, int* __restrict__ counts) {
    int i = blockIdx.x * blockDim.x + threadIdx.x;
    int stride = gridDim.x * blockDim.x;
    for (int e = i; e < N_EDGES; e += stride) atomicAdd(&counts[dst[e]], 1);
}

// phase A: per-block (256-wide) reduction of counts -> blocksum[b]
__global__ __launch_bounds__(256) void scanA_kernel(const int* __restrict__ counts,
                                                    int* __restrict__ blocksum) {
    __shared__ int buf[256];
    int t = threadIdx.x, b = blockIdx.x;
    int i = b * 256 + t;
    int v = (i < N_NODES) ? counts[i] : 0;
    buf[t] = v;
    __syncthreads();
    for (int off = 128; off > 0; off >>= 1) {
        if (t < off) buf[t] += buf[t + off];
        __syncthreads();
    }
    if (t == 0) blocksum[b] = buf[0];
}

// phase B: single small block scans the NB_SCAN block sums -> exclusive blockoff
__global__ __launch_bounds__(256) void scanB_kernel(const int* __restrict__ blocksum,
                                                    int* __restrict__ blockoff,
                                                    int* __restrict__ row_ptr) {
    __shared__ int buf[256];
    int t = threadIdx.x;
    int v = (t < NB_SCAN) ? blocksum[t] : 0;
    buf[t] = v;
    __syncthreads();
    for (int off = 1; off < 256; off <<= 1) {
        int u = (t >= off) ? buf[t - off] : 0;
        __syncthreads();
        buf[t] += u;
        __syncthreads();
    }
    if (t < NB_SCAN) blockoff[t] = buf[t] - v;  // exclusive
    if (t == NB_SCAN - 1) row_ptr[N_NODES] = buf[t];
}

// phase C: per-block exclusive scan + add block offset -> row_ptr, cursor
__global__ __launch_bounds__(256) void scanC_kernel(const int* __restrict__ counts,
                                                    const int* __restrict__ blockoff,
                                                    int* __restrict__ row_ptr,
                                                    int* __restrict__ cursor) {
    __shared__ int buf[256];
    int t = threadIdx.x, b = blockIdx.x;
    int i = b * 256 + t;
    int v = (i < N_NODES) ? counts[i] : 0;
    buf[t] = v;
    __syncthreads();
    for (int off = 1; off < 256; off <<= 1) {
        int u = (t >= off) ? buf[t - off] : 0;
        __syncthreads();
        buf[t] += u;
        __syncthreads();
    }
    if (i < N_NODES) {
        int e = blockoff[b] + buf[t] - v;
        row_ptr[i] = e;
        cursor[i] = e;
    }
}

// fused edge metadata: {src, weight-bits}
__global__ void fill_kernel(const int* __restrict__ src, const int* __restrict__ dst,
                            const float* __restrict__ w, int* __restrict__ cursor,
                            int2* __restrict__ em) {
    int i = blockIdx.x * blockDim.x + threadIdx.x;
    int stride = gridDim.x * blockDim.x;
    for (int e = i; e < N_EDGES; e += stride) {
        int d = dst[e];
        int p = atomicAdd(&cursor[d], 1);
        em[p] = make_int2(src[e], __float_as_int(w[e]));
    }
}

// ---------------------------------------------------------------- GEMM
// xw[v][c] = sum_k (hraw[v][k]*scale[k]+shift[k]) * W[k][c], output fp16.
__global__ __launch_bounds__(256) void gemm_kernel(const float* __restrict__ hraw,
                                                   const float* __restrict__ bnsum_p,
                                                   const float* __restrict__ gamma_p,
                                                   const float* __restrict__ beta_p,
                                                   const float* __restrict__ Wl,
                                                   __half* __restrict__ xw) {
    __shared__ float aff[2][D];
    int tid = threadIdx.x, lane = tid & 63, wave = tid >> 6;
    if (tid < D) {
        float sc = 1.f, sh = 0.f;
        if (bnsum_p) bn_affine(bnsum_p, gamma_p, beta_p, tid, sc, sh);
        aff[0][tid] = sc;
        aff[1][tid] = sh;
    }
    __syncthreads();
    float Wreg[D];
    float biasc = 0.f;
#pragma unroll
    for (int k = 0; k < D; k++) {
        float wkc = Wl[k * D + lane];
        biasc = fmaf(aff[1][k], wkc, biasc);
        Wreg[k] = wkc * aff[0][k];
    }
    int gw = blockIdx.x * 4 + wave, nw = gridDim.x * 4;
    for (int v = gw; v < N_NODES; v += nw) {
        const float* hp = hraw + (size_t)__builtin_amdgcn_readfirstlane(v) * D;
        float acc = biasc;
#pragma unroll
        for (int k = 0; k < D; k++) acc = fmaf(hp[k], Wreg[k], acc);
        xw[v * D + lane] = __float2half_rn(acc);
    }
}

// ---------------------------------------------------------------- aggregate
// One wave per dst node, lane = feature. Unroll-8, two fma chains, fp16 gather.
__global__ __launch_bounds__(256) void agg_kernel(const __half* __restrict__ xw,
                                                  const int* __restrict__ row_ptr,
                                                  const int2* __restrict__ em,
                                                  const float* __restrict__ bl,
                                                  const float* __restrict__ pa,
                                                  const float* __restrict__ hraw_prev,
                                                  const float* __restrict__ bnsum_p,
                                                  const float* __restrict__ gamma_p,
                                                  const float* __restrict__ beta_p,
                                                  float* __restrict__ hpre,
                                                  float* __restrict__ bnsum) {
    int tid = threadIdx.x, lane = tid & 63, wave = tid >> 6;
    int gw = blockIdx.x * 4 + wave, nw = gridDim.x * 4;
    float al = pa[0];
    float bias = bl[lane];
    float sc = 0.f, sh = 0.f;
    if (hraw_prev) bn_affine(bnsum_p, gamma_p, beta_p, lane, sc, sh);
    float s1 = 0.f, s2 = 0.f;
    for (int v = gw; v < N_NODES; v += nw) {
        int e0 = row_ptr[v], e1 = row_ptr[v + 1];
        float acc0 = bias, acc1 = 0.f;
        int e = e0;
        for (; e + 8 <= e1; e += 8) {
            int2 m0 = em[e + 0], m1 = em[e + 1], m2 = em[e + 2], m3 = em[e + 3];
            int2 m4 = em[e + 4], m5 = em[e + 5], m6 = em[e + 6], m7 = em[e + 7];
            float x0 = __half2float(xw[m0.x * D + lane]);
            float x1 = __half2float(xw[m1.x * D + lane]);
            float x2 = __half2float(xw[m2.x * D + lane]);
            float x3 = __half2float(xw[m3.x * D + lane]);
            float x4 = __half2float(xw[m4.x * D + lane]);
            float x5 = __half2float(xw[m5.x * D + lane]);
            float x6 = __half2float(xw[m6.x * D + lane]);
            float x7 = __half2float(xw[m7.x * D + lane]);
            acc0 = fmaf(__int_as_float(m0.y), x0, acc0);
            acc1 = fmaf(__int_as_float(m1.y), x1, acc1);
            acc0 = fmaf(__int_as_float(m2.y), x2, acc0);
            acc1 = fmaf(__int_as_float(m3.y), x3, acc1);
            acc0 = fmaf(__int_as_float(m4.y), x4, acc0);
            acc1 = fmaf(__int_as_float(m5.y), x5, acc1);
            acc0 = fmaf(__int_as_float(m6.y), x6, acc0);
            acc1 = fmaf(__int_as_float(m7.y), x7, acc1);
        }
        for (; e + 2 <= e1; e += 2) {
            int2 m0 = em[e + 0], m1 = em[e + 1];
            float x0 = __half2float(xw[m0.x * D + lane]);
            float x1 = __half2float(xw[m1.x * D + lane]);
            acc0 = fmaf(__int_as_float(m0.y), x0, acc0);
            acc1 = fmaf(__int_as_float(m1.y), x1, acc1);
        }
        if (e < e1) {
            int2 m0 = em[e];
            acc0 = fmaf(__int_as_float(m0.y), __half2float(xw[m0.x * D + lane]), acc0);
        }
        float acc = acc0 + acc1;
        float h = acc >= 0.f ? acc : al * acc;
        if (hraw_prev) h = fmaf(hraw_prev[v * D + lane], sc, h + sh);
        hpre[v * D + lane] = h;
        s1 += h;
        s2 = fmaf(h, h, s2);
    }
    __shared__ float red[8][D];
    red[wave][lane] = s1;
    red[4 + wave][lane] = s2;
    __syncthreads();
    if (wave == 0) {
        float t1 = red[0][lane] + red[1][lane] + red[2][lane] + red[3][lane];
        float t2 = red[4][lane] + red[5][lane] + red[6][lane] + red[7][lane];
        atomicAdd(&bnsum[lane], t1);
        atomicAdd(&bnsum[D + lane], t2);
    }
}

// ---------------------------------------------------------------- final BN apply
__global__ __launch_bounds__(256) void bnapply_kernel(const float* __restrict__ hpre,
                                                      const float* __restrict__ bnsum_p,
                                                      const float* __restrict__ gamma_p,
                                                      const float* __restrict__ beta_p,
                                                      float* __restrict__ out) {
    __shared__ float aff[2][D];
    int tid = threadIdx.x;
    if (tid < D) {
        float sc, sh;
        bn_affine(bnsum_p, gamma_p, beta_p, tid, sc, sh);
        aff[0][tid] = sc;
        aff[1][tid] = sh;
    }
    __syncthreads();
    int i = blockIdx.x * blockDim.x + tid;
    int stride = gridDim.x * blockDim.x;
    const int NQ = N_NODES * D / 4;
    for (int j = i; j < NQ; j += stride) {
        float4 hv = ((const float4*)hpre)[j];
        int c = (j * 4) & 63;
        float4 o;
        o.x = fmaf(hv.x, aff[0][c + 0], aff[1][c + 0]);
        o.y = fmaf(hv.y, aff[0][c + 1], aff[1][c + 1]);
        o.z = fmaf(hv.z, aff[0][c + 2], aff[1][c + 2]);
        o.w = fmaf(hv.w, aff[0][c + 3], aff[1][c + 3]);
        ((float4*)out)[j] = o;
    }
}

// ---------------------------------------------------------------- launch
extern "C" void kernel_launch(void* const* d_in, const int* in_sizes, int n_in,
                              void* d_out, int out_size, void* d_ws, size_t ws_size,
                              hipStream_t stream) {
    const float* x     = (const float*)d_in[0];
    const int*   esrc  = (const int*)d_in[1];
    const int*   edst  = (const int*)d_in[2];
    const float* ew    = (const float*)d_in[3];
    const float* W     = (const float*)d_in[4];
    const float* b     = (const float*)d_in[5];
    const float* pa    = (const float*)d_in[6];
    const float* gamma = (const float*)d_in[7];
    const float* beta  = (const float*)d_in[8];
    float* out = (float*)d_out;

    char* ws = (char*)d_ws;
    size_t off = 0;
    auto alloc = [&](size_t bytes) -> char* {
        char* p = ws + off;
        off = (off + bytes + 255) & ~(size_t)255;
        return p;
    };
    int*   counts   = (int*)alloc((size_t)N_NODES * 4);
    int*   row_ptr  = (int*)alloc((size_t)(N_NODES + 1) * 4);
    int*   cursor   = (int*)alloc((size_t)N_NODES * 4);
    int*   blocksum = (int*)alloc((size_t)NB_SCAN * 4);
    int*   blockoff = (int*)alloc((size_t)NB_SCAN * 4);
    int2*  em       = (int2*)alloc((size_t)N_EDGES * 8);
    __half* xw      = (__half*)alloc((size_t)N_NODES * D * 2);
    float* hpre1    = (float*)alloc((size_t)N_NODES * D * 4);
    float* bnsum    = (float*)alloc((size_t)L * 2 * D * 4);

    init_kernel<<<256, 256, 0, stream>>>(counts, bnsum);
    count_kernel<<<2048, 256, 0, stream>>>(edst, counts);
    scanA_kernel<<<NB_SCAN, 256, 0, stream>>>(counts, blocksum);
    scanB_kernel<<<1, 256, 0, stream>>>(blocksum, blockoff, row_ptr);
    scanC_kernel<<<NB_SCAN, 256, 0, stream>>>(counts, blockoff, row_ptr, cursor);
    fill_kernel<<<2048, 256, 0, stream>>>(esrc, edst, ew, cursor, em);

    // hpre storage: layer0 -> d_out, layer1 -> ws, layer2 -> d_out
    float* hbuf[L] = {out, hpre1, out};
    for (int i = 0; i < L; i++) {
        const float* hin = (i == 0) ? x : hbuf[i - 1];
        const float* bns = (i == 0) ? nullptr : bnsum + (i - 1) * 2 * D;
        const float* gmp = (i == 0) ? nullptr : gamma + (i - 1) * D;
        const float* btp = (i == 0) ? nullptr : beta + (i - 1) * D;
        gemm_kernel<<<512, 256, 0, stream>>>(hin, bns, gmp, btp, W + (size_t)i * D * D, xw);
        agg_kernel<<<2048, 256, 0, stream>>>(xw, row_ptr, em, b + i * D, pa + i,
                                             (i == 0) ? nullptr : hbuf[i - 1],
                                             bns, gmp, btp,
                                             hbuf[i], bnsum + i * 2 * D);
    }
    bnapply_kernel<<<2048, 256, 0, stream>>>(hbuf[2], bnsum + 2 * 2 * D,
                                             gamma + 2 * D, beta + 2 * D, out);
}

// Round 4
// 351.658 us; speedup vs baseline: 1.6123x; 1.1550x over previous
//
#include <hip/hip_runtime.h>
#include <hip/hip_fp16.h>

#define N_NODES 50000
#define N_EDGES 1000000
#define D 64
#define L 3
#define BN_EPS 1e-5f
#define NB_SCAN ((N_NODES + 255) / 256)  // 196 blocks of 256

// ---------------------------------------------------------------- helpers
__device__ inline void bn_affine(const float* __restrict__ bnsum,
                                 const float* __restrict__ gamma,
                                 const float* __restrict__ beta,
                                 int c, float& sc, float& sh) {
    float mean = bnsum[c] * (1.f / N_NODES);
    float var = fmaf(-mean, mean, bnsum[D + c] * (1.f / N_NODES));
    float inv = rsqrtf(var + BN_EPS);
    sc = gamma[c] * inv;
    sh = fmaf(-mean, sc, beta[c]);
}

__device__ inline float unpack_w(unsigned int m) {
    __half_raw hr;
    hr.x = (unsigned short)(m & 0xffffu);
    __half h = *reinterpret_cast<__half*>(&hr);
    return __half2float(h);
}

__device__ inline float2 unpack_x2(unsigned int q) {
    __half2 h2 = *reinterpret_cast<__half2*>(&q);
    return __half22float2(h2);
}

// ---------------------------------------------------------------- init
__global__ void init_kernel(int* __restrict__ counts, float* __restrict__ bnsum) {
    int i = blockIdx.x * blockDim.x + threadIdx.x;
    int stride = gridDim.x * blockDim.x;
    for (int j = i; j < N_NODES; j += stride) counts[j] = 0;
    for (int j = i; j < L * 2 * D; j += stride) bnsum[j] = 0.f;
}

// ---------------------------------------------------------------- CSR build
// count + per-edge rank (position within its dst bucket)
__global__ void count_kernel(const int* __restrict__ dst, int* __restrict__ counts,
                             unsigned short* __restrict__ rank) {
    int i = blockIdx.x * blockDim.x + threadIdx.x;
    int stride = gridDim.x * blockDim.x;
    for (int e = i; e < N_EDGES; e += stride) {
        int r = atomicAdd(&counts[dst[e]], 1);
        rank[e] = (unsigned short)r;
    }
}

// phase A: per-block (256-wide) reduction of counts -> blocksum[b]
__global__ __launch_bounds__(256) void scanA_kernel(const int* __restrict__ counts,
                                                    int* __restrict__ blocksum) {
    __shared__ int buf[256];
    int t = threadIdx.x, b = blockIdx.x;
    int i = b * 256 + t;
    int v = (i < N_NODES) ? counts[i] : 0;
    buf[t] = v;
    __syncthreads();
    for (int off = 128; off > 0; off >>= 1) {
        if (t < off) buf[t] += buf[t + off];
        __syncthreads();
    }
    if (t == 0) blocksum[b] = buf[0];
}

// phase B: single block scans the NB_SCAN block sums -> exclusive blockoff
__global__ __launch_bounds__(256) void scanB_kernel(const int* __restrict__ blocksum,
                                                    int* __restrict__ blockoff,
                                                    int* __restrict__ row_ptr) {
    __shared__ int buf[256];
    int t = threadIdx.x;
    int v = (t < NB_SCAN) ? blocksum[t] : 0;
    buf[t] = v;
    __syncthreads();
    for (int off = 1; off < 256; off <<= 1) {
        int u = (t >= off) ? buf[t - off] : 0;
        __syncthreads();
        buf[t] += u;
        __syncthreads();
    }
    if (t < NB_SCAN) blockoff[t] = buf[t] - v;  // exclusive
    if (t == NB_SCAN - 1) row_ptr[N_NODES] = buf[t];
}

// phase C: per-block exclusive scan + add block offset -> row_ptr
__global__ __launch_bounds__(256) void scanC_kernel(const int* __restrict__ counts,
                                                    const int* __restrict__ blockoff,
                                                    int* __restrict__ row_ptr) {
    __shared__ int buf[256];
    int t = threadIdx.x, b = blockIdx.x;
    int i = b * 256 + t;
    int v = (i < N_NODES) ? counts[i] : 0;
    buf[t] = v;
    __syncthreads();
    for (int off = 1; off < 256; off <<= 1) {
        int u = (t >= off) ? buf[t - off] : 0;
        __syncthreads();
        buf[t] += u;
        __syncthreads();
    }
    if (i < N_NODES) row_ptr[i] = blockoff[b] + buf[t] - v;
}

// scatter edges into dst-sorted order; no atomics (rank precomputed)
__global__ void fill_kernel(const int* __restrict__ src, const int* __restrict__ dst,
                            const float* __restrict__ w,
                            const unsigned short* __restrict__ rank,
                            const int* __restrict__ row_ptr,
                            unsigned int* __restrict__ em) {
    int i = blockIdx.x * blockDim.x + threadIdx.x;
    int stride = gridDim.x * blockDim.x;
    for (int e = i; e < N_EDGES; e += stride) {
        int d = dst[e];
        int p = row_ptr[d] + (int)rank[e];
        __half h = __float2half_rn(w[e]);
        unsigned short wb = reinterpret_cast<__half_raw*>(&h)->x;
        em[p] = ((unsigned int)src[e] << 16) | (unsigned int)wb;
    }
}

// ---------------------------------------------------------------- GEMM
// xw[v][c] = sum_k (hraw[v][k]*scale[k]+shift[k]) * W[k][c], output fp16.
__global__ __launch_bounds__(256) void gemm_kernel(const float* __restrict__ hraw,
                                                   const float* __restrict__ bnsum_p,
                                                   const float* __restrict__ gamma_p,
                                                   const float* __restrict__ beta_p,
                                                   const float* __restrict__ Wl,
                                                   __half* __restrict__ xw) {
    __shared__ float aff[2][D];
    int tid = threadIdx.x, lane = tid & 63, wave = tid >> 6;
    if (tid < D) {
        float sc = 1.f, sh = 0.f;
        if (bnsum_p) bn_affine(bnsum_p, gamma_p, beta_p, tid, sc, sh);
        aff[0][tid] = sc;
        aff[1][tid] = sh;
    }
    __syncthreads();
    float Wreg[D];
    float biasc = 0.f;
#pragma unroll
    for (int k = 0; k < D; k++) {
        float wkc = Wl[k * D + lane];
        biasc = fmaf(aff[1][k], wkc, biasc);
        Wreg[k] = wkc * aff[0][k];
    }
    int gw = blockIdx.x * 4 + wave, nw = gridDim.x * 4;
    for (int v = gw; v < N_NODES; v += nw) {
        const float* hp = hraw + (size_t)__builtin_amdgcn_readfirstlane(v) * D;
        float acc = biasc;
#pragma unroll
        for (int k = 0; k < D; k++) acc = fmaf(hp[k], Wreg[k], acc);
        xw[v * D + lane] = __float2half_rn(acc);
    }
}

// ---------------------------------------------------------------- aggregate
// One wave per dst node; half-wave per edge (2 edges in flight per gather).
// Lane l: half = l>>5, fl = l&31 -> features {2fl, 2fl+1} of edge (e + half).
__global__ __launch_bounds__(256) void agg_kernel(const unsigned int* __restrict__ xw,
                                                  const int* __restrict__ row_ptr,
                                                  const unsigned int* __restrict__ em,
                                                  const float* __restrict__ bl,
                                                  const float* __restrict__ pa,
                                                  const float* __restrict__ hraw_prev,
                                                  const float* __restrict__ bnsum_p,
                                                  const float* __restrict__ gamma_p,
                                                  const float* __restrict__ beta_p,
                                                  float* __restrict__ hpre,
                                                  float* __restrict__ bnsum) {
    int tid = threadIdx.x, lane = tid & 63, wave = tid >> 6;
    int half = lane >> 5, fl = lane & 31;
    int gw = blockIdx.x * 4 + wave, nw = gridDim.x * 4;
    float al = pa[0];
    float2 bias = ((const float2*)bl)[fl];
    float sc0 = 0.f, sh0 = 0.f, sc1 = 0.f, sh1 = 0.f;
    if (hraw_prev) {
        bn_affine(bnsum_p, gamma_p, beta_p, 2 * fl, sc0, sh0);
        bn_affine(bnsum_p, gamma_p, beta_p, 2 * fl + 1, sc1, sh1);
    }
    float s1x = 0.f, s1y = 0.f, s2x = 0.f, s2y = 0.f;
    for (int v = gw; v < N_NODES; v += nw) {
        int e0 = row_ptr[v], e1 = row_ptr[v + 1];
        float ax0 = 0.f, ay0 = 0.f, ax1 = 0.f, ay1 = 0.f;
        int e = e0;
        for (; e + 8 <= e1; e += 8) {
            unsigned int m0 = em[e + 0 + half], m1 = em[e + 2 + half];
            unsigned int m2 = em[e + 4 + half], m3 = em[e + 6 + half];
            unsigned int q0 = xw[(m0 >> 16) * 32 + fl];
            unsigned int q1 = xw[(m1 >> 16) * 32 + fl];
            unsigned int q2 = xw[(m2 >> 16) * 32 + fl];
            unsigned int q3 = xw[(m3 >> 16) * 32 + fl];
            float w0 = unpack_w(m0), w1 = unpack_w(m1), w2 = unpack_w(m2), w3 = unpack_w(m3);
            float2 f0 = unpack_x2(q0), f1 = unpack_x2(q1), f2 = unpack_x2(q2), f3 = unpack_x2(q3);
            ax0 = fmaf(w0, f0.x, ax0); ay0 = fmaf(w0, f0.y, ay0);
            ax1 = fmaf(w1, f1.x, ax1); ay1 = fmaf(w1, f1.y, ay1);
            ax0 = fmaf(w2, f2.x, ax0); ay0 = fmaf(w2, f2.y, ay0);
            ax1 = fmaf(w3, f3.x, ax1); ay1 = fmaf(w3, f3.y, ay1);
        }
        for (; e < e1; e += 2) {
            int idx = e + half;
            if (idx < e1) {
                unsigned int m = em[idx];
                unsigned int q = xw[(m >> 16) * 32 + fl];
                float wv = unpack_w(m);
                float2 f = unpack_x2(q);
                ax0 = fmaf(wv, f.x, ax0);
                ay0 = fmaf(wv, f.y, ay0);
            }
        }
        float ax = ax0 + ax1, ay = ay0 + ay1;
        ax += __shfl_xor(ax, 32, 64);
        ay += __shfl_xor(ay, 32, 64);
        if (half == 0) {
            ax += bias.x;
            ay += bias.y;
            float hx = ax >= 0.f ? ax : al * ax;
            float hy = ay >= 0.f ? ay : al * ay;
            if (hraw_prev) {
                float2 hp = ((const float2*)hraw_prev)[v * 32 + fl];
                hx = fmaf(hp.x, sc0, hx + sh0);
                hy = fmaf(hp.y, sc1, hy + sh1);
            }
            ((float2*)hpre)[v * 32 + fl] = make_float2(hx, hy);
            s1x += hx; s1y += hy;
            s2x = fmaf(hx, hx, s2x);
            s2y = fmaf(hy, hy, s2y);
        }
    }
    __shared__ float red[8][D];
    if (half == 0) {
        red[wave][2 * fl] = s1x;
        red[wave][2 * fl + 1] = s1y;
        red[4 + wave][2 * fl] = s2x;
        red[4 + wave][2 * fl + 1] = s2y;
    }
    __syncthreads();
    if (wave == 0) {
        float t1 = red[0][lane] + red[1][lane] + red[2][lane] + red[3][lane];
        float t2 = red[4][lane] + red[5][lane] + red[6][lane] + red[7][lane];
        atomicAdd(&bnsum[lane], t1);
        atomicAdd(&bnsum[D + lane], t2);
    }
}

// ---------------------------------------------------------------- final BN apply
__global__ __launch_bounds__(256) void bnapply_kernel(const float* __restrict__ hpre,
                                                      const float* __restrict__ bnsum_p,
                                                      const float* __restrict__ gamma_p,
                                                      const float* __restrict__ beta_p,
                                                      float* __restrict__ out) {
    __shared__ float aff[2][D];
    int tid = threadIdx.x;
    if (tid < D) {
        float sc, sh;
        bn_affine(bnsum_p, gamma_p, beta_p, tid, sc, sh);
        aff[0][tid] = sc;
        aff[1][tid] = sh;
    }
    __syncthreads();
    int i = blockIdx.x * blockDim.x + tid;
    int stride = gridDim.x * blockDim.x;
    const int NQ = N_NODES * D / 4;
    for (int j = i; j < NQ; j += stride) {
        float4 hv = ((const float4*)hpre)[j];
        int c = (j * 4) & 63;
        float4 o;
        o.x = fmaf(hv.x, aff[0][c + 0], aff[1][c + 0]);
        o.y = fmaf(hv.y, aff[0][c + 1], aff[1][c + 1]);
        o.z = fmaf(hv.z, aff[0][c + 2], aff[1][c + 2]);
        o.w = fmaf(hv.w, aff[0][c + 3], aff[1][c + 3]);
        ((float4*)out)[j] = o;
    }
}

// ---------------------------------------------------------------- launch
extern "C" void kernel_launch(void* const* d_in, const int* in_sizes, int n_in,
                              void* d_out, int out_size, void* d_ws, size_t ws_size,
                              hipStream_t stream) {
    const float* x     = (const float*)d_in[0];
    const int*   esrc  = (const int*)d_in[1];
    const int*   edst  = (const int*)d_in[2];
    const float* ew    = (const float*)d_in[3];
    const float* W     = (const float*)d_in[4];
    const float* b     = (const float*)d_in[5];
    const float* pa    = (const float*)d_in[6];
    const float* gamma = (const float*)d_in[7];
    const float* beta  = (const float*)d_in[8];
    float* out = (float*)d_out;

    char* ws = (char*)d_ws;
    size_t off = 0;
    auto alloc = [&](size_t bytes) -> char* {
        char* p = ws + off;
        off = (off + bytes + 255) & ~(size_t)255;
        return p;
    };
    int*            counts   = (int*)alloc((size_t)N_NODES * 4);
    int*            row_ptr  = (int*)alloc((size_t)(N_NODES + 1) * 4);
    int*            blocksum = (int*)alloc((size_t)NB_SCAN * 4);
    int*            blockoff = (int*)alloc((size_t)NB_SCAN * 4);
    unsigned short* rank     = (unsigned short*)alloc((size_t)N_EDGES * 2);
    unsigned int*   em       = (unsigned int*)alloc((size_t)N_EDGES * 4);
    __half*         xw       = (__half*)alloc((size_t)N_NODES * D * 2);
    float*          hpre1    = (float*)alloc((size_t)N_NODES * D * 4);
    float*          bnsum    = (float*)alloc((size_t)L * 2 * D * 4);

    init_kernel<<<256, 256, 0, stream>>>(counts, bnsum);
    count_kernel<<<2048, 256, 0, stream>>>(edst, counts, rank);
    scanA_kernel<<<NB_SCAN, 256, 0, stream>>>(counts, blocksum);
    scanB_kernel<<<1, 256, 0, stream>>>(blocksum, blockoff, row_ptr);
    scanC_kernel<<<NB_SCAN, 256, 0, stream>>>(counts, blockoff, row_ptr);
    fill_kernel<<<2048, 256, 0, stream>>>(esrc, edst, ew, rank, row_ptr, em);

    // hpre storage: layer0 -> d_out, layer1 -> ws, layer2 -> d_out
    float* hbuf[L] = {out, hpre1, out};
    for (int i = 0; i < L; i++) {
        const float* hin = (i == 0) ? x : hbuf[i - 1];
        const float* bns = (i == 0) ? nullptr : bnsum + (i - 1) * 2 * D;
        const float* gmp = (i == 0) ? nullptr : gamma + (i - 1) * D;
        const float* btp = (i == 0) ? nullptr : beta + (i - 1) * D;
        gemm_kernel<<<512, 256, 0, stream>>>(hin, bns, gmp, btp, W + (size_t)i * D * D, xw);
        agg_kernel<<<2048, 256, 0, stream>>>((const unsigned int*)xw, row_ptr, em,
                                             b + i * D, pa + i,
                                             (i == 0) ? nullptr : hbuf[i - 1],
                                             bns, gmp, btp,
                                             hbuf[i], bnsum + i * 2 * D);
    }
    bnapply_kernel<<<2048, 256, 0, stream>>>(hbuf[2], bnsum + 2 * 2 * D,
                                             gamma + 2 * D, beta + 2 * D, out);
}